// Round 1
// baseline (313.326 us; speedup 1.0000x reference)
//
#include <hip/hip_runtime.h>

// ---------- types ----------
typedef __attribute__((ext_vector_type(4))) float f32x4;
typedef __attribute__((ext_vector_type(8))) short bf16x8;

__device__ __forceinline__ unsigned short f2bf(float f) {
    union { float f; unsigned u; } v; v.f = f;
    unsigned r = v.u + 0x7FFFu + ((v.u >> 16) & 1u);   // RTNE
    return (unsigned short)(r >> 16);
}

#define GLD16(gp, lp)                                                          \
    __builtin_amdgcn_global_load_lds(                                          \
        (const __attribute__((address_space(1))) void*)(gp),                   \
        (__attribute__((address_space(3))) void*)(lp), 16, 0, 0)

// ---------- elementwise: f32 -> bf16 (vectorized float4) ----------
__global__ void k_cvt(const float* __restrict__ in, unsigned short* __restrict__ out, int n4) {
    int i = blockIdx.x * blockDim.x + threadIdx.x;
    int stride = gridDim.x * blockDim.x;
    for (; i < n4; i += stride) {
        float4 v = reinterpret_cast<const float4*>(in)[i];
        ushort4 o;
        o.x = f2bf(v.x); o.y = f2bf(v.y); o.z = f2bf(v.z); o.w = f2bf(v.w);
        reinterpret_cast<ushort4*>(out)[i] = o;
    }
}

// ---------- elementwise: logbias = log(max(cutoffs, 1e-15)) ----------
__global__ void k_log(const float* __restrict__ in, float* __restrict__ out, int n4) {
    int i = blockIdx.x * blockDim.x + threadIdx.x;
    int stride = gridDim.x * blockDim.x;
    for (; i < n4; i += stride) {
        float4 v = reinterpret_cast<const float4*>(in)[i];
        float4 o;
        o.x = __logf(fmaxf(v.x, 1e-15f));
        o.y = __logf(fmaxf(v.y, 1e-15f));
        o.z = __logf(fmaxf(v.z, 1e-15f));
        o.w = __logf(fmaxf(v.w, 1e-15f));
        reinterpret_cast<float4*>(out)[i] = o;
    }
}

// ---------- GEMM: C = A(MxK) * B(NxK)^T + bias, bf16 in, m97 structure ----------
// MODE 0: write fp32 out[m*N+n]  (out-projection)
// MODE 1: scatter bf16 into q[BH,T,D], k[BH,T,D], v[BH,D,T]  (QKV projection)
template <int MODE>
__global__ __launch_bounds__(256) void gemm_bt(
    const unsigned short* __restrict__ A, const unsigned short* __restrict__ B,
    const float* __restrict__ bias, float* __restrict__ outf,
    unsigned short* __restrict__ qb, unsigned short* __restrict__ kb,
    unsigned short* __restrict__ vb, int M, int N, int K)
{
    __shared__ unsigned short sA[128 * 32];
    __shared__ unsigned short sB[128 * 32];
    const int tid = threadIdx.x;
    const int w = tid >> 6, lane = tid & 63, g = lane >> 4, r = lane & 15;
    const int tm = blockIdx.x * 128, tn = blockIdx.y * 128;
    const int wr = w >> 1, wc = w & 1;

    f32x4 acc[4][4];
#pragma unroll
    for (int i = 0; i < 4; i++)
#pragma unroll
        for (int j = 0; j < 4; j++) acc[i][j] = (f32x4)0.f;

    const unsigned short* ga0 = A + (size_t)(tm + w * 32 + (lane >> 2)) * K + (lane & 3) * 8;
    const unsigned short* gb0 = B + (size_t)(tn + w * 32 + (lane >> 2)) * K + (lane & 3) * 8;
    unsigned short* la = sA + w * 32 * 32;
    unsigned short* lb = sB + w * 32 * 32;

    for (int kk = 0; kk < K; kk += 32) {
        __syncthreads();
        GLD16(ga0 + kk, la);
        GLD16(ga0 + kk + (size_t)16 * K, la + 16 * 32);
        GLD16(gb0 + kk, lb);
        GLD16(gb0 + kk + (size_t)16 * K, lb + 16 * 32);
        __syncthreads();
        bf16x8 af[4], bfv[4];
#pragma unroll
        for (int f = 0; f < 4; f++) af[f] = *(const bf16x8*)&sA[(wr * 64 + f * 16 + r) * 32 + g * 8];
#pragma unroll
        for (int f = 0; f < 4; f++) bfv[f] = *(const bf16x8*)&sB[(wc * 64 + f * 16 + r) * 32 + g * 8];
#pragma unroll
        for (int i = 0; i < 4; i++)
#pragma unroll
            for (int j = 0; j < 4; j++)
                acc[i][j] = __builtin_amdgcn_mfma_f32_16x16x32_bf16(af[i], bfv[j], acc[i][j], 0, 0, 0);
    }

#pragma unroll
    for (int fj = 0; fj < 4; fj++) {
        int n = tn + wc * 64 + fj * 16 + r;
        float bn = bias[n];
#pragma unroll
        for (int fi = 0; fi < 4; fi++) {
#pragma unroll
            for (int j = 0; j < 4; j++) {
                int m = tm + wr * 64 + fi * 16 + 4 * g + j;
                float v = acc[fi][fj][j] + bn;
                if (MODE == 0) {
                    outf[(size_t)m * N + n] = v;
                } else {
                    int three = n >> 10, h = (n >> 6) & 15, d = n & 63;
                    int b = m >> 11, t = m & 2047, bh = b * 16 + h;
                    unsigned short bv = f2bf(v);
                    if (three == 0)      qb[((size_t)bh * 2048 + t) * 64 + d] = bv;
                    else if (three == 1) kb[((size_t)bh * 2048 + t) * 64 + d] = bv;
                    else                 vb[((size_t)bh * 64 + d) * 2048 + t] = bv;  // V transposed
                }
            }
        }
    }
}

// ---------- flash attention ----------
// grid (T/64, H, B), 256 threads (4 waves). Wave w owns q rows [w*16, w*16+16).
// LDS tiles are [64 rows][64 bf16] with XOR swizzle: element e of row at e ^ ((row&7)<<3).
// Staging pre-swizzles the GLOBAL source chunk so global_load_lds stays linear (m173 pattern).
__global__ __launch_bounds__(256) void attn_kernel(
    const unsigned short* __restrict__ qbuf, const unsigned short* __restrict__ kbuf,
    const unsigned short* __restrict__ vbuf, const float* __restrict__ logbias,
    unsigned short* __restrict__ outa)
{
    __shared__ unsigned short sQ[64 * 64], sK[64 * 64], sV[64 * 64], sP[4 * 16 * 64];
    const int tid = threadIdx.x, w = tid >> 6, lane = tid & 63, g = lane >> 4, r = lane & 15;
    const int qt = blockIdx.x, h = blockIdx.y, b = blockIdx.z;
    const int q0 = qt * 64, bh = b * 16 + h;

    // stage Q (once)
    {
        int c = lane & 7;
#pragma unroll
        for (int i = 0; i < 2; i++) {
            int row = w * 16 + i * 8 + (lane >> 3);
            GLD16(qbuf + ((size_t)bh * 2048 + q0 + row) * 64 + (c ^ (row & 7)) * 8,
                  sQ + (w * 16 + i * 8) * 64);
        }
    }
    __syncthreads();
    bf16x8 aq[2];
    {
        int qrow = w * 16 + r;
#pragma unroll
        for (int s = 0; s < 2; s++)
            aq[s] = *(const bf16x8*)&sQ[qrow * 64 + ((s * 32 + g * 8) ^ ((qrow & 7) << 3))];
    }

    f32x4 oacc[4];
#pragma unroll
    for (int f = 0; f < 4; f++) oacc[f] = (f32x4)0.f;
    float mrow[4], lrow[4];
#pragma unroll
    for (int j = 0; j < 4; j++) { mrow[j] = -1e30f; lrow[j] = 0.f; }

    unsigned short* sPw = sP + w * 16 * 64;

    for (int kt = 0; kt < 32; kt++) {
        __syncthreads();
        // stage K tile [k][d] and V^T tile [d][t], pre-swizzled source
        {
            int c = lane & 7;
#pragma unroll
            for (int i = 0; i < 2; i++) {
                int row = w * 16 + i * 8 + (lane >> 3);
                GLD16(kbuf + ((size_t)bh * 2048 + kt * 64 + row) * 64 + (c ^ (row & 7)) * 8,
                      sK + (w * 16 + i * 8) * 64);
                GLD16(vbuf + ((size_t)bh * 64 + row) * 2048 + kt * 64 + (c ^ (row & 7)) * 8,
                      sV + (w * 16 + i * 8) * 64);
            }
        }
        // bias prefetch (hits L2/L3; reused across 16 heads)
        float bias[4][4];
#pragma unroll
        for (int f = 0; f < 4; f++)
#pragma unroll
            for (int j = 0; j < 4; j++)
                bias[f][j] = logbias[((size_t)b * 2048 + (q0 + w * 16 + 4 * g + j)) * 2048
                                     + kt * 64 + f * 16 + r];
        __syncthreads();

        // S = Q K^T  (8 MFMAs)
        f32x4 sa[4];
#pragma unroll
        for (int f = 0; f < 4; f++) sa[f] = (f32x4)0.f;
#pragma unroll
        for (int s = 0; s < 2; s++)
#pragma unroll
            for (int f = 0; f < 4; f++) {
                int krow = f * 16 + r;
                bf16x8 bk = *(const bf16x8*)&sK[krow * 64 + ((s * 32 + g * 8) ^ ((krow & 7) << 3))];
                sa[f] = __builtin_amdgcn_mfma_f32_16x16x32_bf16(aq[s], bk, sa[f], 0, 0, 0);
            }

        // online softmax (fp32, wave-parallel row reduce over 16 lanes)
        float sv[4][4];
#pragma unroll
        for (int f = 0; f < 4; f++)
#pragma unroll
            for (int j = 0; j < 4; j++) sv[f][j] = sa[f][j] * 0.125f + bias[f][j];

        float alpha[4], psum[4];
#pragma unroll
        for (int j = 0; j < 4; j++) {
            float pm = fmaxf(fmaxf(sv[0][j], sv[1][j]), fmaxf(sv[2][j], sv[3][j]));
            pm = fmaxf(pm, __shfl_xor(pm, 1));
            pm = fmaxf(pm, __shfl_xor(pm, 2));
            pm = fmaxf(pm, __shfl_xor(pm, 4));
            pm = fmaxf(pm, __shfl_xor(pm, 8));
            float mnew = fmaxf(mrow[j], pm);
            alpha[j] = __expf(mrow[j] - mnew);
            mrow[j] = mnew;
            psum[j] = 0.f;
        }
#pragma unroll
        for (int f = 0; f < 4; f++)
#pragma unroll
            for (int j = 0; j < 4; j++) {
                float p = __expf(sv[f][j] - mrow[j]);
                psum[j] += p;
                int row = 4 * g + j, col = f * 16 + r;
                sPw[row * 64 + (col ^ ((row & 7) << 3))] = f2bf(p);
            }
#pragma unroll
        for (int j = 0; j < 4; j++) {
            psum[j] += __shfl_xor(psum[j], 1);
            psum[j] += __shfl_xor(psum[j], 2);
            psum[j] += __shfl_xor(psum[j], 4);
            psum[j] += __shfl_xor(psum[j], 8);
            lrow[j] = lrow[j] * alpha[j] + psum[j];
            oacc[0][j] *= alpha[j]; oacc[1][j] *= alpha[j];
            oacc[2][j] *= alpha[j]; oacc[3][j] *= alpha[j];
        }

        // PV (8 MFMAs); P round-trips via wave-private LDS (compiler orders ds_write->ds_read)
#pragma unroll
        for (int s = 0; s < 2; s++) {
            bf16x8 pa = *(const bf16x8*)&sPw[r * 64 + ((s * 32 + g * 8) ^ ((r & 7) << 3))];
#pragma unroll
            for (int f = 0; f < 4; f++) {
                int drow = f * 16 + r;
                bf16x8 bvv = *(const bf16x8*)&sV[drow * 64 + ((s * 32 + g * 8) ^ ((drow & 7) << 3))];
                oacc[f] = __builtin_amdgcn_mfma_f32_16x16x32_bf16(pa, bvv, oacc[f], 0, 0, 0);
            }
        }
    }

    // epilogue: normalize, write bf16 [B,T,H*D]
#pragma unroll
    for (int j = 0; j < 4; j++) {
        float inv = 1.f / lrow[j];
        int q = q0 + w * 16 + 4 * g + j;
#pragma unroll
        for (int f = 0; f < 4; f++) {
            int d = f * 16 + r;
            outa[((size_t)(b * 2048 + q)) * 1024 + h * 64 + d] = f2bf(oacc[f][j] * inv);
        }
    }
}

// ---------- launch ----------
extern "C" void kernel_launch(void* const* d_in, const int* in_sizes, int n_in,
                              void* d_out, int out_size, void* d_ws, size_t ws_size,
                              hipStream_t stream) {
    const float* x       = (const float*)d_in[0];
    const float* cutoffs = (const float*)d_in[1];
    const float* Wqkv    = (const float*)d_in[2];
    const float* bqkv    = (const float*)d_in[3];
    const float* Wout    = (const float*)d_in[4];
    const float* bout    = (const float*)d_in[5];
    float* out = (float*)d_out;

    char* ws = (char*)d_ws;
    float* logbias = (float*)ws;                    ws += (size_t)2 * 2048 * 2048 * 4;  // 33.5 MB
    unsigned short* x_bf    = (unsigned short*)ws;  ws += (size_t)4096 * 1024 * 2;
    unsigned short* wqkv_bf = (unsigned short*)ws;  ws += (size_t)3072 * 1024 * 2;
    unsigned short* wout_bf = (unsigned short*)ws;  ws += (size_t)1024 * 1024 * 2;
    unsigned short* qb      = (unsigned short*)ws;  ws += (size_t)32 * 2048 * 64 * 2;
    unsigned short* kb      = (unsigned short*)ws;  ws += (size_t)32 * 2048 * 64 * 2;
    unsigned short* vb      = (unsigned short*)ws;  ws += (size_t)32 * 2048 * 64 * 2;
    unsigned short* attn_o  = (unsigned short*)ws;  ws += (size_t)4096 * 1024 * 2;      // total 80 MB

    k_cvt<<<1024, 256, 0, stream>>>(x,    x_bf,    4096 * 1024 / 4);
    k_cvt<<<1024, 256, 0, stream>>>(Wqkv, wqkv_bf, 3072 * 1024 / 4);
    k_cvt<<<512,  256, 0, stream>>>(Wout, wout_bf, 1024 * 1024 / 4);
    k_log<<<2048, 256, 0, stream>>>(cutoffs, logbias, 2 * 2048 * 2048 / 4);

    gemm_bt<1><<<dim3(32, 24), 256, 0, stream>>>(x_bf, wqkv_bf, bqkv, nullptr,
                                                 qb, kb, vb, 4096, 3072, 1024);
    attn_kernel<<<dim3(32, 16, 2), 256, 0, stream>>>(qb, kb, vb, logbias, attn_o);
    gemm_bt<0><<<dim3(32, 8), 256, 0, stream>>>(attn_o, wout_bf, bout, out,
                                                nullptr, nullptr, nullptr, 4096, 1024, 1024);
}